// Round 5
// baseline (354.727 us; speedup 1.0000x reference)
//
#include <hip/hip_runtime.h>
#include <hip/hip_bf16.h>
#include <stdint.h>

#define IN_F   4096
#define OUT_F  4096
#define BATCHN 8192

#define BK   64
#define NTK  (IN_F / BK)       // 64 K-tiles
#define HOFF (128 * IN_F)      // half-tile (128 rows) offset in elements

using f32x4 = __attribute__((ext_vector_type(4))) float;
using f16x8 = __attribute__((ext_vector_type(8))) _Float16;
using i32x4 = __attribute__((ext_vector_type(4))) int;
using u32x4 = __attribute__((ext_vector_type(4))) unsigned int;

__device__ __forceinline__ void stg(const _Float16* src, int kelem, char* sm, int dstoff) {
    __builtin_amdgcn_global_load_lds(
        (const __attribute__((address_space(1))) void*)(src + kelem),
        (__attribute__((address_space(3))) void*)(sm + dstoff), 16, 0, 0);
}

__device__ __forceinline__ u32x4 pack8_f16(const float* v) {
    union { _Float16 h[8]; u32x4 u; } p;
#pragma unroll
    for (int i = 0; i < 8; ++i) p.h[i] = (_Float16)v[i];
    return p.u;
}

// ---------------------------------------------------------------------------
// Fused prep: blocks [0,8192): build W (fp16); [8192,24576): convert x;
// [24576,24592): bias.
// ---------------------------------------------------------------------------
__global__ __launch_bounds__(256) void prep(const float* __restrict__ hw,
                                            const float* __restrict__ xiW,
                                            const int*   __restrict__ idxW,
                                            u32x4* __restrict__ Wh,
                                            const float* __restrict__ x,
                                            u32x4* __restrict__ Xh,
                                            const float* __restrict__ hb,
                                            const float* __restrict__ xiB,
                                            const int*   __restrict__ idxB,
                                            float* __restrict__ bias) {
    const int b = blockIdx.x;
    if (b < 8192) {
        size_t t = (size_t)b * 256 + threadIdx.x;
        size_t base = t * 8;
        i32x4 i0 = *(const i32x4*)(idxW + base);
        i32x4 i1 = *(const i32x4*)(idxW + base + 4);
        f32x4 s0 = *(const f32x4*)(xiW + base);
        f32x4 s1 = *(const f32x4*)(xiW + base + 4);
        float v[8];
        v[0] = hw[i0[0]] * s0[0];
        v[1] = hw[i0[1]] * s0[1];
        v[2] = hw[i0[2]] * s0[2];
        v[3] = hw[i0[3]] * s0[3];
        v[4] = hw[i1[0]] * s1[0];
        v[5] = hw[i1[1]] * s1[1];
        v[6] = hw[i1[2]] * s1[2];
        v[7] = hw[i1[3]] * s1[3];
        Wh[t] = pack8_f16(v);
    } else if (b < 24576) {
        size_t t = (size_t)(b - 8192) * 256 + threadIdx.x;
        size_t base = t * 8;
        f32x4 a = *(const f32x4*)(x + base);
        f32x4 c = *(const f32x4*)(x + base + 4);
        float v[8] = {a[0], a[1], a[2], a[3], c[0], c[1], c[2], c[3]};
        Xh[t] = pack8_f16(v);
    } else {
        int o = (b - 24576) * 256 + threadIdx.x;
        if (o < OUT_F) bias[o] = hb[idxB[o]] * xiB[o];
    }
}

// ---------------------------------------------------------------------------
// 256x256x64 GEMM, fp16 MFMA, fp32 out + bias.
// All ds_reads hoisted ONE PHASE ahead of their consuming MFMA cluster;
// unroll-2 main loop (static buffer bases, imm stage offsets), peeled tail.
// Per tile T (cur = buf[T&1], nxt = other; all stages target T+2 -> cur):
//   ph0: rd bF23(T)+aFhi(T) | Q00(aFlo,bF01) | stg T+2.Blo
//   ph1:                    | Q01(aFlo,bF23) | stg T+2.Bhi | vmcnt(4)
//   ph2: rd aFlo(T+1) (nxt) | Q10(aFhi,bF01) | stg T+2.Alo
//   ph3: rd bF01(T+1) (nxt) | Q11(aFhi,bF23) | stg T+2.Ahi
// WAR: B-region reads end at T.ph0 -> B stages at ph0c/ph1c legal;
// A-region reads end at T.ph0 (aFhi) -> A stages at ph2c/ph3c legal.
// vmcnt(4)@ph1c retires all 8 of T+1 (staged during T-1) before ph2's
// nxt-reads; leaves T+2.{Blo,Bhi}=4 in flight; ph2c/ph3c restore 8.
// Swizzle: phys = linear ^ ((row&7)<<4), inverse on global src, fwd on reads.
// ---------------------------------------------------------------------------
__global__ __launch_bounds__(512, 2) void gemm_8ph(const _Float16* __restrict__ A,
                                                   const _Float16* __restrict__ Bm,
                                                   const float*    __restrict__ bias,
                                                   float*          __restrict__ C) {
    extern __shared__ char smem[];
    const int tid  = threadIdx.x;
    const int lane = tid & 63;
    const int wave = tid >> 6;
    const int wr   = wave >> 2;
    const int wc   = wave & 3;

    const int bid   = blockIdx.x;
    const int xcd   = bid & 7;
    const int local = bid >> 3;
    const int m_idx = (xcd & 3) * 8 + (local & 7);
    const int n_idx = (xcd >> 2) * 8 + (local >> 3);
    const size_t brow = (size_t)m_idx * 256;
    const size_t bcol = (size_t)n_idx * 256;

    const int srow = tid >> 3;
    const int scol = ((tid & 7) ^ (srow & 7)) << 3;
    const _Float16* aS0 = A  + (brow + srow)      * IN_F + scol;
    const _Float16* aS1 = A  + (brow + 64 + srow) * IN_F + scol;
    const _Float16* bS0 = Bm + (bcol + srow)      * IN_F + scol;
    const _Float16* bS1 = Bm + (bcol + 64 + srow) * IN_F + scol;
    const _Float16* aS0h = aS0 + HOFF;
    const _Float16* aS1h = aS1 + HOFF;
    const _Float16* bS0h = bS0 + HOFF;
    const _Float16* bS1h = bS1 + HOFF;
    const int dA = tid << 4;
    const int dB = 32768 + (tid << 4);

    const int rrow = lane & 15;
    const int pc0  = (((lane >> 4))     ^ (lane & 7)) << 4;
    const int pc1  = ((4 + (lane >> 4)) ^ (lane & 7)) << 4;
    const int aAd0 = (wr * 128 + rrow) * 128 + pc0;
    const int aAd1 = (wr * 128 + rrow) * 128 + pc1;
    const int bAd0 = 32768 + (wc * 64 + rrow) * 128 + pc0;
    const int bAd1 = 32768 + (wc * 64 + rrow) * 128 + pc1;

    f32x4 acc[8][4];
#pragma unroll
    for (int m = 0; m < 8; ++m)
#pragma unroll
        for (int n = 0; n < 4; ++n) acc[m][n] = (f32x4){0.f, 0.f, 0.f, 0.f};

    f16x8 aFlo[4][2], aFhi[4][2], bF[4][2];

#define OB() do { __builtin_amdgcn_s_barrier(); __builtin_amdgcn_sched_barrier(0); } while (0)
#define CB() do { __builtin_amdgcn_sched_barrier(0); __builtin_amdgcn_s_barrier(); \
                  __builtin_amdgcn_sched_barrier(0); } while (0)

#define MQ(M0, N0, AF) do { \
    _Pragma("unroll") \
    for (int ks = 0; ks < 2; ++ks) { \
        _Pragma("unroll") \
        for (int i = 0; i < 4; ++i) { \
            _Pragma("unroll") \
            for (int nn = 0; nn < 2; ++nn) \
                acc[(M0) + i][(N0) + nn] = __builtin_amdgcn_mfma_f32_16x16x32_f16( \
                    AF[i][ks], bF[(N0) + nn][ks], acc[(M0) + i][(N0) + nn], 0, 0, 0); \
        } } } while (0)

#define GTILE(CURB, KO, STGON, VM, RDNXT) { \
    const int AC0 = aAd0 + (CURB), AC1 = aAd1 + (CURB); \
    const int BC0 = bAd0 + (CURB), BC1 = bAd1 + (CURB); \
    const int AN0 = aAd0 + ((CURB) ^ 65536), AN1 = aAd1 + ((CURB) ^ 65536); \
    const int BN0 = bAd0 + ((CURB) ^ 65536), BN1 = bAd1 + ((CURB) ^ 65536); \
    /* ph0 */ \
    OB(); \
    bF[2][0] = *(const f16x8*)(smem + BC0 + 4096); \
    bF[3][0] = *(const f16x8*)(smem + BC0 + 6144); \
    bF[2][1] = *(const f16x8*)(smem + BC1 + 4096); \
    bF[3][1] = *(const f16x8*)(smem + BC1 + 6144); \
    aFhi[0][0] = *(const f16x8*)(smem + AC0 + 8192); \
    aFhi[1][0] = *(const f16x8*)(smem + AC0 + 10240); \
    aFhi[2][0] = *(const f16x8*)(smem + AC0 + 12288); \
    aFhi[3][0] = *(const f16x8*)(smem + AC0 + 14336); \
    aFhi[0][1] = *(const f16x8*)(smem + AC1 + 8192); \
    aFhi[1][1] = *(const f16x8*)(smem + AC1 + 10240); \
    aFhi[2][1] = *(const f16x8*)(smem + AC1 + 12288); \
    aFhi[3][1] = *(const f16x8*)(smem + AC1 + 14336); \
    __builtin_amdgcn_s_setprio(1); \
    MQ(0, 0, aFlo); \
    __builtin_amdgcn_s_setprio(0); \
    CB(); \
    if (STGON) { stg(bS0, KO, smem, (CURB) + dB); \
                 stg(bS1, KO, smem, (CURB) + dB + 8192); } \
    /* ph1 */ \
    OB(); \
    __builtin_amdgcn_s_setprio(1); \
    MQ(0, 2, aFlo); \
    __builtin_amdgcn_s_setprio(0); \
    CB(); \
    if (STGON) { stg(bS0h, KO, smem, (CURB) + dB + 16384); \
                 stg(bS1h, KO, smem, (CURB) + dB + 16384 + 8192); } \
    if ((VM) == 4) { asm volatile("s_waitcnt vmcnt(4)" ::: "memory"); } \
    else if ((VM) == 0) { asm volatile("s_waitcnt vmcnt(0)" ::: "memory"); } \
    /* ph2 */ \
    OB(); \
    if (RDNXT) { \
        aFlo[0][0] = *(const f16x8*)(smem + AN0); \
        aFlo[1][0] = *(const f16x8*)(smem + AN0 + 2048); \
        aFlo[2][0] = *(const f16x8*)(smem + AN0 + 4096); \
        aFlo[3][0] = *(const f16x8*)(smem + AN0 + 6144); \
        aFlo[0][1] = *(const f16x8*)(smem + AN1); \
        aFlo[1][1] = *(const f16x8*)(smem + AN1 + 2048); \
        aFlo[2][1] = *(const f16x8*)(smem + AN1 + 4096); \
        aFlo[3][1] = *(const f16x8*)(smem + AN1 + 6144); \
    } \
    __builtin_amdgcn_s_setprio(1); \
    MQ(4, 0, aFhi); \
    __builtin_amdgcn_s_setprio(0); \
    CB(); \
    if (STGON) { stg(aS0, KO, smem, (CURB) + dA); \
                 stg(aS1, KO, smem, (CURB) + dA + 8192); } \
    /* ph3 */ \
    OB(); \
    if (RDNXT) { \
        bF[0][0] = *(const f16x8*)(smem + BN0); \
        bF[1][0] = *(const f16x8*)(smem + BN0 + 2048); \
        bF[0][1] = *(const f16x8*)(smem + BN1); \
        bF[1][1] = *(const f16x8*)(smem + BN1 + 2048); \
    } \
    __builtin_amdgcn_s_setprio(1); \
    MQ(4, 2, aFhi); \
    __builtin_amdgcn_s_setprio(0); \
    CB(); \
    if (STGON) { stg(aS0h, KO, smem, (CURB) + dA + 16384); \
                 stg(aS1h, KO, smem, (CURB) + dA + 16384 + 8192); } \
}

    // --- prologue: stage T0 (buf0) + T1 (buf1) fully; land T0; carried reads
    stg(aS0, 0, smem, dA);
    stg(aS1, 0, smem, dA + 8192);
    stg(aS0h, 0, smem, dA + 16384);
    stg(aS1h, 0, smem, dA + 16384 + 8192);
    stg(bS0, 0, smem, dB);
    stg(bS1, 0, smem, dB + 8192);
    stg(bS0h, 0, smem, dB + 16384);
    stg(bS1h, 0, smem, dB + 16384 + 8192);
    stg(bS0, 64, smem, 65536 + dB);
    stg(bS1, 64, smem, 65536 + dB + 8192);
    stg(bS0h, 64, smem, 65536 + dB + 16384);
    stg(bS1h, 64, smem, 65536 + dB + 16384 + 8192);
    stg(aS0, 64, smem, 65536 + dA);
    stg(aS1, 64, smem, 65536 + dA + 8192);
    stg(aS0h, 64, smem, 65536 + dA + 16384);
    stg(aS1h, 64, smem, 65536 + dA + 16384 + 8192);
    asm volatile("s_waitcnt vmcnt(8)" ::: "memory");   // T0 landed; T1 (8) in flight
    __builtin_amdgcn_sched_barrier(0);
    __builtin_amdgcn_s_barrier();
    __builtin_amdgcn_sched_barrier(0);
    // carried fragment set for T0's Q00/Q10: aFlo(T0) + bF01(T0)
    aFlo[0][0] = *(const f16x8*)(smem + aAd0);
    aFlo[1][0] = *(const f16x8*)(smem + aAd0 + 2048);
    aFlo[2][0] = *(const f16x8*)(smem + aAd0 + 4096);
    aFlo[3][0] = *(const f16x8*)(smem + aAd0 + 6144);
    aFlo[0][1] = *(const f16x8*)(smem + aAd1);
    aFlo[1][1] = *(const f16x8*)(smem + aAd1 + 2048);
    aFlo[2][1] = *(const f16x8*)(smem + aAd1 + 4096);
    aFlo[3][1] = *(const f16x8*)(smem + aAd1 + 6144);
    bF[0][0] = *(const f16x8*)(smem + bAd0);
    bF[1][0] = *(const f16x8*)(smem + bAd0 + 2048);
    bF[0][1] = *(const f16x8*)(smem + bAd1);
    bF[1][1] = *(const f16x8*)(smem + bAd1 + 2048);

    // --- main loop: tiles 0..61, unroll 2 (buf0 then buf1), full staging
    for (int kt = 0; kt < NTK - 2; kt += 2) {
        GTILE(0,     128, 1, 4, 1);
        GTILE(65536, 192, 1, 4, 1);
        aS0 += 128; aS1 += 128; bS0 += 128; bS1 += 128;
        aS0h += 128; aS1h += 128; bS0h += 128; bS1h += 128;
    }
    // --- tail: tile 62 (no stages, drain, read T63), tile 63 (compute only)
    GTILE(0,     0, 0, 0,  1);
    GTILE(65536, 0, 0, -1, 0);

#undef GTILE
#undef MQ
#undef OB
#undef CB

    // --- epilogue: C/D layout col = lane&15, row = (lane>>4)*4 + j ---
    const int crow = (lane >> 4) << 2;
    const int ccol = lane & 15;
#pragma unroll
    for (int n = 0; n < 4; ++n) {
        const size_t col = bcol + wc * 64 + n * 16 + ccol;
        const float bv = bias[col];
#pragma unroll
        for (int m = 0; m < 8; ++m) {
            const size_t row = brow + wr * 128 + m * 16 + crow;
            float* cp = C + row * OUT_F + col;
#pragma unroll
            for (int j = 0; j < 4; ++j)
                cp[(size_t)j * OUT_F] = acc[m][n][j] + bv;
        }
    }
}

// ---------------------------------------------------------------------------
extern "C" void kernel_launch(void* const* d_in, const int* in_sizes, int n_in,
                              void* d_out, int out_size, void* d_ws, size_t ws_size,
                              hipStream_t stream) {
    const float* x    = (const float*)d_in[0];
    const float* hw   = (const float*)d_in[1];
    const float* hb   = (const float*)d_in[2];
    const float* xiW  = (const float*)d_in[3];
    const float* xiB  = (const float*)d_in[4];
    const int*   idxW = (const int*)d_in[5];
    const int*   idxB = (const int*)d_in[6];
    float* out = (float*)d_out;

    char* ws = (char*)d_ws;
    _Float16* Wh  = (_Float16*)ws;                                   // 32 MB
    _Float16* Xh  = (_Float16*)(ws + (size_t)32 * 1024 * 1024);      // 64 MB
    float*    bia = (float*)   (ws + (size_t)96 * 1024 * 1024);      // 16 KB

    (void)hipFuncSetAttribute((const void*)gemm_8ph,
                              hipFuncAttributeMaxDynamicSharedMemorySize, 131072);

    prep<<<24592, 256, 0, stream>>>(hw, xiW, idxW, (u32x4*)Wh,
                                    x, (u32x4*)Xh, hb, xiB, idxB, bia);
    gemm_8ph<<<512, 512, 131072, stream>>>(Xh, Wh, bia, out);
}